// Round 14
// baseline (416.286 us; speedup 1.0000x reference)
//
#include <hip/hip_runtime.h>
#include <hip/hip_bf16.h>

// Problem constants
#define L_  4
#define G_  20000
#define C_  128
#define E_  320000
#define KD_ 16
#define LC_ 512            // L_*C_
#define DECAY_ 0.5f
#define LN_EPS_ 1e-5f
#define NG_ 16             // g's per final block (64 rows)

// bf16 helpers: cur rows stored as 64 x uint4 (8 bf16 per uint4, 1KB/row)
__device__ __forceinline__ float bflo(unsigned u) { return __uint_as_float(u << 16); }
__device__ __forceinline__ float bfhi(unsigned u) { return __uint_as_float(u & 0xFFFF0000u); }
__device__ __forceinline__ unsigned pack_bf2(float a, float b) {
    __hip_bfloat16 ha = __float2bfloat16(a), hb = __float2bfloat16(b);
    unsigned short ua = *reinterpret_cast<unsigned short*>(&ha);
    unsigned short ub = *reinterpret_cast<unsigned short*>(&hb);
    return (unsigned)ua | ((unsigned)ub << 16);
}

// ---------------------------------------------------------------------------
// init: cur0[g] = bf16(x); kq0[g][j] = (K[j], Q[j]) interleaved f32, j=l*16+kd;
// weights[g*4+l] = mean_kd(K*Q). 64 threads, one g. Weights stay f32 (LN
// cancels |w| -> w needs ABSOLUTE accuracy; bf16 w was R10's 4.95 failure).
// ---------------------------------------------------------------------------
__global__ __launch_bounds__(64) void init_kernel(
        const float* __restrict__ x,
        const float* __restrict__ Wk,
        const float* __restrict__ Wq,
        uint4* __restrict__ cur0,
        float2* __restrict__ kq0,
        float* __restrict__ weights) {
    const int g = blockIdx.x;
    const int t = threadIdx.x;
    const int l = t >> 4;
    const int ch = (t & 15) * 8;

    __shared__ float xs[4][132];   // +4 pad -> conflict-free

    const float4* xr = (const float4*)(x + ((size_t)l * G_ + g) * C_ + ch);
    float4 xa = xr[0], xb = xr[1];
    *(float4*)&xs[l][ch]     = xa;
    *(float4*)&xs[l][ch + 4] = xb;

    uint4 o;
    o.x = pack_bf2(xa.x, xa.y);
    o.y = pack_bf2(xa.z, xa.w);
    o.z = pack_bf2(xb.x, xb.y);
    o.w = pack_bf2(xb.z, xb.w);
    cur0[(size_t)g * 64 + t] = o;
    __syncthreads();

    // projection: lane t -> (l = t>>4, kd = t&15); j = t
    const int kd = t & 15;
    const float* xrow = xs[l];
    float K = 0.f, Q = 0.f;
#pragma unroll 8
    for (int c = 0; c < C_; ++c) {
        float xv = xrow[c];
        K += xv * Wk[c * KD_ + kd];
        Q += xv * Wq[c * KD_ + kd];
    }
    kq0[(size_t)g * 64 + t] = make_float2(K, Q);

    float prod = K * Q;
#pragma unroll
    for (int m = 1; m < 16; m <<= 1) prod += __shfl_xor(prod, m);
    if ((t & 15) == 0) weights[g * 4 + l] = prod * (1.0f / 16.0f);
}

// ---------------------------------------------------------------------------
// CSR build: hist -> parallel 3-phase scan -> scatter (edges packed int2)
// ---------------------------------------------------------------------------
__global__ void hist_kernel(const int* __restrict__ row, int* __restrict__ counts) {
    int e = blockIdx.x * 256 + threadIdx.x;
    if (e < E_) atomicAdd(&counts[row[e]], 1);
}

__global__ __launch_bounds__(256) void scan_blocks_kernel(
        const int* __restrict__ counts, int* __restrict__ offsets,
        int* __restrict__ btot, int n) {
    const int b = blockIdx.x, t = threadIdx.x;
    const int i = b * 256 + t;
    const int lane = t & 63, wid = t >> 6;
    int v = (i < n) ? counts[i] : 0;
    int incl = v;
#pragma unroll
    for (int d = 1; d < 64; d <<= 1) {
        int o = __shfl_up(incl, d);
        if (lane >= d) incl += o;
    }
    __shared__ int ws[4];
    if (lane == 63) ws[wid] = incl;
    __syncthreads();
    int waveoff = 0;
#pragma unroll
    for (int k = 0; k < 4; ++k) if (k < wid) waveoff += ws[k];
    int excl = waveoff + incl - v;
    if (i < n) offsets[i] = excl;
    if (t == 255) btot[b] = waveoff + incl;
}

__global__ __launch_bounds__(128) void scan_totals_kernel(
        int* __restrict__ btot, int* __restrict__ offsets, int n, int nb) {
    const int t = threadIdx.x;
    const int lane = t & 63, wid = t >> 6;
    int v = (t < nb) ? btot[t] : 0;
    int incl = v;
#pragma unroll
    for (int d = 1; d < 64; d <<= 1) {
        int o = __shfl_up(incl, d);
        if (lane >= d) incl += o;
    }
    __shared__ int ws[2];
    if (lane == 63) ws[wid] = incl;
    __syncthreads();
    int off = (wid == 1) ? ws[0] : 0;
    int excl = off + incl - v;
    if (t < nb) btot[t] = excl;
    if (t == nb - 1) offsets[n] = excl + v;
}

__global__ __launch_bounds__(256) void add_base_kernel(
        int* __restrict__ offsets, const int* __restrict__ btot, int n) {
    int i = blockIdx.x * 256 + threadIdx.x;
    if (i < n) offsets[i] += btot[blockIdx.x];
}

__global__ void scatter_kernel(const int* __restrict__ row,
                               const int* __restrict__ col,
                               const float* __restrict__ vals,
                               int* __restrict__ cursor,
                               int2* __restrict__ edges) {
    int e = blockIdx.x * 256 + threadIdx.x;
    if (e < E_) {
        int r = row[e];
        int pos = atomicAdd(&cursor[r], 1);
        edges[pos] = make_int2(col[e], __float_as_int(vals[e] * DECAY_));
    }
}

// ---------------------------------------------------------------------------
// Sharded SpMM: block b = (gc = b>>3, shard s = b&7). 64 threads = 8 groups
// (one g each: g = gc*8 + grp) x 8 lanes. Lane owns slot = s*8+ln of the
// 64-slot cur (uint4) and kq (float2) rows. With blockIdx%8 -> XCD round-
// robin, each XCD touches only its 3.8MB shard stripe -> L2-resident gathers.
// Edge stream loaded non-temporally (don't thrash the stripe).
// Weights: lane's kq slot j=s*8+ln has complete (K_j,Q_j); shard covers one
// l = s>>1; partial mean over 8 j's -> atomicAdd (2 shards complete each l).
// ---------------------------------------------------------------------------
__global__ __launch_bounds__(64) void spmm_kernel(
        const uint4* __restrict__ cur_in,
        uint4* __restrict__ cur_out,
        const float2* __restrict__ kq_in,
        float2* __restrict__ kq_out,
        const int* __restrict__ offs,
        const int2* __restrict__ edges,
        float* __restrict__ weights) {
    const int b = blockIdx.x;
    const int s = b & 7;
    const int gc = b >> 3;
    const int t = threadIdx.x;
    const int grp = t >> 3, ln = t & 7;
    const int g = gc * 8 + grp;
    const int slot = s * 8 + ln;

    const int sE = offs[g], eE = offs[g + 1];
    float acc[8];
#pragma unroll
    for (int j = 0; j < 8; ++j) acc[j] = 0.f;
    float2 ka = {0.f, 0.f};

    int i = sE;
    for (; i + 4 <= eE; i += 4) {
        int   cole[4];
        float vv[4];
#pragma unroll
        for (int u = 0; u < 4; ++u) {
            long long e8 = __builtin_nontemporal_load(
                (const long long*)(edges + i + u));
            cole[u] = (int)(e8 & 0xffffffffLL);
            vv[u]   = __int_as_float((int)(e8 >> 32));
        }
        uint4  d[4];
        float2 p[4];
#pragma unroll
        for (int u = 0; u < 4; ++u) d[u] = cur_in[(size_t)cole[u] * 64 + slot];
#pragma unroll
        for (int u = 0; u < 4; ++u) p[u] = kq_in[(size_t)cole[u] * 64 + slot];
#pragma unroll
        for (int u = 0; u < 4; ++u) {
            acc[0] += vv[u] * bflo(d[u].x); acc[1] += vv[u] * bfhi(d[u].x);
            acc[2] += vv[u] * bflo(d[u].y); acc[3] += vv[u] * bfhi(d[u].y);
            acc[4] += vv[u] * bflo(d[u].z); acc[5] += vv[u] * bfhi(d[u].z);
            acc[6] += vv[u] * bflo(d[u].w); acc[7] += vv[u] * bfhi(d[u].w);
            ka.x   += vv[u] * p[u].x;
            ka.y   += vv[u] * p[u].y;
        }
    }
    for (; i < eE; ++i) {
        long long e8 = __builtin_nontemporal_load((const long long*)(edges + i));
        int c0 = (int)(e8 & 0xffffffffLL);
        float v0 = __int_as_float((int)(e8 >> 32));
        uint4 d = cur_in[(size_t)c0 * 64 + slot];
        float2 p = kq_in[(size_t)c0 * 64 + slot];
        acc[0] += v0 * bflo(d.x); acc[1] += v0 * bfhi(d.x);
        acc[2] += v0 * bflo(d.y); acc[3] += v0 * bfhi(d.y);
        acc[4] += v0 * bflo(d.z); acc[5] += v0 * bfhi(d.z);
        acc[6] += v0 * bflo(d.w); acc[7] += v0 * bfhi(d.w);
        ka.x   += v0 * p.x;
        ka.y   += v0 * p.y;
    }

    uint4 o;
    o.x = pack_bf2(acc[0], acc[1]);
    o.y = pack_bf2(acc[2], acc[3]);
    o.z = pack_bf2(acc[4], acc[5]);
    o.w = pack_bf2(acc[6], acc[7]);
    cur_out[(size_t)g * 64 + slot] = o;
    kq_out[(size_t)g * 64 + slot] = ka;

    // weights partial: reduce K*Q over the 8 lanes of this group (8 of 16 kd)
    float prod = ka.x * ka.y;
#pragma unroll
    for (int m = 1; m < 8; m <<= 1) prod += __shfl_xor(prod, m);
    if (ln == 0) atomicAdd(&weights[g * 4 + (s >> 1)], prod * (1.0f / 16.0f));
}

// ---------------------------------------------------------------------------
// final: x_acc = x(f32) + cur1(bf16) + cur2(bf16) staged to LDS;
// v = (x_acc @ Wv) * w; LayerNorm; out. 512 threads (8 waves), NG_ g's.
// ---------------------------------------------------------------------------
__global__ __launch_bounds__(512) void final_kernel(
        const float* __restrict__ x,
        const uint4* __restrict__ cur1,
        const uint4* __restrict__ cur2,
        const float* __restrict__ weights,
        const float* __restrict__ Wv,
        const float* __restrict__ gamma,
        const float* __restrict__ beta,
        float* __restrict__ out) {
    const int g0 = blockIdx.x * NG_;
    const int t = threadIdx.x;
    __shared__ float a[NG_ * 4][C_];   // 32 KB
    __shared__ float wsh[NG_ * 4];

    // stage 64 rows x 128 ch: 1024 8-ch chunks, 2 iters of 512
#pragma unroll
    for (int i = 0; i < 2; ++i) {
        int uidx = i * 512 + t;            // 0..1023
        int rid  = uidx >> 4;              // row 0..63 (g_local*4 + l)
        int u16  = uidx & 15;              // 8-ch chunk within row
        int gl = rid >> 2, l = rid & 3;
        const float4* xr = (const float4*)(x + ((size_t)l * G_ + (g0 + gl)) * C_ + u16 * 8);
        float4 xa = xr[0], xb = xr[1];
        size_t ci = ((size_t)g0 * 4 + rid) * 16 + u16;
        uint4 c1 = cur1[ci], c2 = cur2[ci];
        float4 s0, s1;
        s0.x = xa.x + bflo(c1.x) + bflo(c2.x);
        s0.y = xa.y + bfhi(c1.x) + bfhi(c2.x);
        s0.z = xa.z + bflo(c1.y) + bflo(c2.y);
        s0.w = xa.w + bfhi(c1.y) + bfhi(c2.y);
        s1.x = xb.x + bflo(c1.z) + bflo(c2.z);
        s1.y = xb.y + bfhi(c1.z) + bfhi(c2.z);
        s1.z = xb.z + bflo(c1.w) + bflo(c2.w);
        s1.w = xb.w + bfhi(c1.w) + bfhi(c2.w);
        float4* ap = (float4*)(&a[rid][u16 * 8]);
        ap[0] = s0;
        ap[1] = s1;
    }
    if (t < NG_ * 4) wsh[t] = weights[g0 * 4 + t];
    __syncthreads();

    const int r = t >> 5;              // 16 row-groups x 4 rows
    const int cg = t & 31;
    float4 acc[4];
#pragma unroll
    for (int j = 0; j < 4; ++j) acc[j] = {0.f, 0.f, 0.f, 0.f};

    for (int c = 0; c < C_; c += 4) {
        float4 wv0 = *(const float4*)(Wv + (size_t)(c + 0) * C_ + cg * 4);
        float4 wv1 = *(const float4*)(Wv + (size_t)(c + 1) * C_ + cg * 4);
        float4 wv2 = *(const float4*)(Wv + (size_t)(c + 2) * C_ + cg * 4);
        float4 wv3 = *(const float4*)(Wv + (size_t)(c + 3) * C_ + cg * 4);
#pragma unroll
        for (int j = 0; j < 4; ++j) {
            float4 av = *(const float4*)(&a[r * 4 + j][c]);
            acc[j].x += av.x * wv0.x + av.y * wv1.x + av.z * wv2.x + av.w * wv3.x;
            acc[j].y += av.x * wv0.y + av.y * wv1.y + av.z * wv2.y + av.w * wv3.y;
            acc[j].z += av.x * wv0.z + av.y * wv1.z + av.z * wv2.z + av.w * wv3.z;
            acc[j].w += av.x * wv0.w + av.y * wv1.w + av.z * wv2.w + av.w * wv3.w;
        }
    }

    float4 gm = *(const float4*)(gamma + cg * 4);
    float4 bt = *(const float4*)(beta + cg * 4);

#pragma unroll
    for (int j = 0; j < 4; ++j) {
        const int rid = r * 4 + j;
        float w = wsh[rid];
        float4 v = {acc[j].x * w, acc[j].y * w, acc[j].z * w, acc[j].w * w};

        float sum = v.x + v.y + v.z + v.w;
#pragma unroll
        for (int m = 1; m < 32; m <<= 1) sum += __shfl_xor(sum, m);
        float mu = sum * (1.0f / 128.0f);
        float4 d = {v.x - mu, v.y - mu, v.z - mu, v.w - mu};
        float ss = d.x * d.x + d.y * d.y + d.z * d.z + d.w * d.w;
#pragma unroll
        for (int m = 1; m < 32; m <<= 1) ss += __shfl_xor(ss, m);
        float rs = rsqrtf(ss * (1.0f / 128.0f) + LN_EPS_);

        float4 o;
        o.x = d.x * rs * gm.x + bt.x;
        o.y = d.y * rs * gm.y + bt.y;
        o.z = d.z * rs * gm.z + bt.z;
        o.w = d.w * rs * gm.w + bt.w;

        const int g_local = rid >> 2;
        const int l = rid & 3;
        *(float4*)(out + ((size_t)l * G_ + (g0 + g_local)) * C_ + cg * 4) = o;
    }
}

// ---------------------------------------------------------------------------
extern "C" void kernel_launch(void* const* d_in, const int* in_sizes, int n_in,
                              void* d_out, int out_size, void* d_ws, size_t ws_size,
                              hipStream_t stream) {
    const float* x       = (const float*)d_in[0];
    const int*   e_row   = (const int*)d_in[1];
    const int*   e_col   = (const int*)d_in[2];
    const float* e_val   = (const float*)d_in[3];
    const float* Wk      = (const float*)d_in[4];
    const float* Wq      = (const float*)d_in[5];
    const float* Wv      = (const float*)d_in[6];
    const float* gamma   = (const float*)d_in[7];
    const float* beta    = (const float*)d_in[8];
    float* out = (float*)d_out;

    // workspace bump allocator (256B aligned)
    char* p = (char*)d_ws;
    auto alloc = [&](size_t bytes) -> void* {
        void* r = (void*)p;
        p += (bytes + 255) & ~(size_t)255;
        return r;
    };
    uint4*  cur0    = (uint4*)alloc((size_t)G_ * LC_ * 2);   // bf16 rows (values)
    uint4*  cur1    = (uint4*)alloc((size_t)G_ * LC_ * 2);
    uint4*  cur2    = (uint4*)alloc((size_t)G_ * LC_ * 2);
    float2* kq0     = (float2*)alloc((size_t)G_ * 64 * 8);   // interleaved (K,Q)
    float2* kq1     = (float2*)alloc((size_t)G_ * 64 * 8);
    float2* kq2     = (float2*)alloc((size_t)G_ * 64 * 8);
    float*  weights = (float*)alloc((size_t)G_ * L_ * 4);
    int*    counts  = (int*)alloc((size_t)G_ * 4);
    int*    offsets = (int*)alloc((size_t)(G_ + 1) * 4);
    int*    cursor  = (int*)alloc((size_t)G_ * 4);
    int2*   edges   = (int2*)alloc((size_t)E_ * 8);
    const int NB    = (G_ + 255) / 256;
    int*    btot    = (int*)alloc((size_t)NB * 4);

    // CSR build
    hipMemsetAsync(counts, 0, (size_t)G_ * 4, stream);
    hist_kernel<<<(E_ + 255) / 256, 256, 0, stream>>>(e_row, counts);
    scan_blocks_kernel<<<NB, 256, 0, stream>>>(counts, offsets, btot, G_);
    scan_totals_kernel<<<1, 128, 0, stream>>>(btot, offsets, G_, NB);
    add_base_kernel<<<NB, 256, 0, stream>>>(offsets, btot, G_);
    hipMemcpyAsync(cursor, offsets, (size_t)G_ * 4, hipMemcpyDeviceToDevice, stream);
    scatter_kernel<<<(E_ + 255) / 256, 256, 0, stream>>>(e_row, e_col, e_val,
                                                         cursor, edges);

    // transpose + bf16 cur0 + interleaved f32 (K,Q) + weights0
    init_kernel<<<G_, 64, 0, stream>>>(x, Wk, Wq, cur0, kq0, weights);

    // iterations: XCD-sharded fused SpMM (values bf16 + weights f32)
    spmm_kernel<<<G_, 64, 0, stream>>>(cur0, cur1, kq0, kq1,
                                       offsets, edges, weights);
    spmm_kernel<<<G_, 64, 0, stream>>>(cur1, cur2, kq1, kq2,
                                       offsets, edges, weights);

    // x_acc = x + cur1 + cur2; values @ Wv; LayerNorm
    final_kernel<<<G_ / NG_, 512, 0, stream>>>(x, cur1, cur2, weights, Wv,
                                               gamma, beta, out);
}